// Round 8
// baseline (29.677 us; speedup 1.0000x reference)
//
#include <hip/hip_runtime.h>

// out[b,n] = q^T W_n p ; p=emb[b,R(n)], q=emb[b,C(n)], W_n=kern[:,n,:]
// R8: serial-chain shaving inside the R7 structure.
//  - LUT pair decode (scalar load) replaces SALU while-loop.
//  - per-sub hoisted LDS reads (2 b128 + 4 b64 outstanding together).
//  - s_setprio(1) around the 8-MFMA burst.
//  - epilogue: 4 independent partial dots + tree reduce.
// Layouts identical to R7 (verified): kb fragment-ordered, ebf chunk-swizzled,
// global_load_lds staging, swizzled ds_reads, W ping-pong dbuf.

#define B_TOT 2048
#define NF    32
#define EMB   64
#define NP    496
#define BT    32

typedef short bf16x8 __attribute__((ext_vector_type(8)));
typedef short bf16x4 __attribute__((ext_vector_type(4)));
typedef float f32x4  __attribute__((ext_vector_type(4)));

static __device__ inline unsigned f2bf(float f) {          // RNE f32->bf16
    unsigned u = __builtin_bit_cast(unsigned, f);
    u += 0x7fffu + ((u >> 16) & 1u);
    return u >> 16;
}
static __device__ inline unsigned pack2(float lo, float hi) {
    return f2bf(lo) | (f2bf(hi) << 16);
}
static __device__ inline float bf2f(short s) {
    return __builtin_bit_cast(float, (unsigned)((unsigned short)s) << 16);
}

#define AS1 __attribute__((address_space(1)))
#define AS3 __attribute__((address_space(3)))

// triu16 pair decode LUT: byte = lr*16 + lc for pig 0..119
__device__ const unsigned char PAIR_T16[120] = {
    0x01,0x02,0x03,0x04,0x05,0x06,0x07,0x08,0x09,0x0A,0x0B,0x0C,0x0D,0x0E,0x0F,
    0x12,0x13,0x14,0x15,0x16,0x17,0x18,0x19,0x1A,0x1B,0x1C,0x1D,0x1E,0x1F,
    0x23,0x24,0x25,0x26,0x27,0x28,0x29,0x2A,0x2B,0x2C,0x2D,0x2E,0x2F,
    0x34,0x35,0x36,0x37,0x38,0x39,0x3A,0x3B,0x3C,0x3D,0x3E,0x3F,
    0x45,0x46,0x47,0x48,0x49,0x4A,0x4B,0x4C,0x4D,0x4E,0x4F,
    0x56,0x57,0x58,0x59,0x5A,0x5B,0x5C,0x5D,0x5E,0x5F,
    0x67,0x68,0x69,0x6A,0x6B,0x6C,0x6D,0x6E,0x6F,
    0x78,0x79,0x7A,0x7B,0x7C,0x7D,0x7E,0x7F,
    0x89,0x8A,0x8B,0x8C,0x8D,0x8E,0x8F,
    0x9A,0x9B,0x9C,0x9D,0x9E,0x9F,
    0xAB,0xAC,0xAD,0xAE,0xAF,
    0xBC,0xBD,0xBE,0xBF,
    0xCD,0xCE,0xCF,
    0xDE,0xDF,
    0xEF
};

// ---- fused prep: blocks [0,496) = kern cvt ; blocks [496, 496+2048) = emb cvt
__global__ __launch_bounds__(256) void prep(const float* __restrict__ kern,
                                            const float* __restrict__ emb,
                                            short* __restrict__ kb,
                                            short* __restrict__ ebf) {
    __shared__ short w[EMB * 72];
    if (blockIdx.x < NP) {
        const int n = blockIdx.x;
#pragma unroll
        for (int j = 0; j < 4; ++j) {
            const int idx = threadIdx.x + 256 * j;        // (h, e4)
            const int h = idx >> 4, e4 = idx & 15;
            const f32x4 v = *(const f32x4*)(kern + ((size_t)h * NP + n) * EMB + e4 * 4);
            uint2 u;
            u.x = pack2(v[0], v[1]);
            u.y = pack2(v[2], v[3]);
            *(uint2*)&w[h * 72 + e4 * 4] = u;
        }
        __syncthreads();
#pragma unroll
        for (int j = 0; j < 2; ++j) {
            const int u    = threadIdx.x + 256 * j;       // fragment-lane unit
            const int frag = u >> 6, l = u & 63;
            const int h  = (frag >> 1) * 16 + (l & 15);
            const int e0 = (frag & 1) * 32 + (l >> 4) * 8;
            const bf16x8 t = *(const bf16x8*)&w[h * 72 + e0];
            *(bf16x8*)(kb + (size_t)n * 4096 + u * 8) = t;
        }
    } else {
        // emb -> chunk-swizzled bf16
        const int t    = (blockIdx.x - NP) * 256 + threadIdx.x;  // 0..524287
        const int cidx = t & 127;
        const int f    = (t >> 7) & 31;
        const int bt16 = t >> 12;
        const int bp = cidx >> 3, x = cidx & 7;
        const int ec = x ^ (bp & 7);
        const float* src = emb + (((size_t)(bt16 * 16 + bp) * NF + f) * EMB + ec * 8);
        const f32x4 a = *(const f32x4*)src;
        const f32x4 b = *(const f32x4*)(src + 4);
        uint4 u;
        u.x = pack2(a[0], a[1]); u.y = pack2(a[2], a[3]);
        u.z = pack2(b[0], b[1]); u.w = pack2(b[2], b[3]);
        *(uint4*)(ebf + (size_t)t * 8) = u;
    }
}

__global__ __launch_bounds__(512, 4) void opnl_main(
    const short* __restrict__ ebf,   // [B/16][NF][128 chunks x 8 shorts] swizzled
    const short* __restrict__ kb,    // [NP][8][64][8] bf16 fragment order
    float* __restrict__ out)         // [B][NP] f32
{
    __shared__ short elds[16 * 2 * 1024];    // 32 segs x 2KB = 64KB

    const int type = blockIdx.x >> 6;        // 0..7
    const int bt   = blockIdx.x & 63;        // b-tile; bid%8 = bt%8 -> XCD share
    const int b0   = bt * BT;

    int bLo, bHi, npr;
    switch (type) {
        case 0: case 1: bLo = 0;  bHi = 0;  npr = 60; break;  // fields 0..15
        case 2: case 3: bLo = 16; bHi = 16; npr = 60; break;  // fields 16..31
        case 4:         bLo = 0;  bHi = 8;  npr = 64; break;
        case 5:         bLo = 8;  bHi = 16; npr = 64; break;
        case 6:         bLo = 0;  bHi = 16; npr = 64; break;
        default:        bLo = 8;  bHi = 8;  npr = 64; break;
    }

    const int lane = threadIdx.x & 63;
    const int wid  = threadIdx.x >> 6;       // 0..7
    const int lo4  = lane & 15;
    const int hi4  = lane >> 4;

    // ---- stage: wave w copies segs 4w..4w+3 (seg = lf*2+sub), 2x 1KB each
#pragma unroll
    for (int i = 0; i < 4; ++i) {
        const int s   = wid * 4 + i;
        const int lf  = s >> 1, sub = s & 1;
        const int gf  = lf + (lf < 8 ? bLo : bHi);
        const short* src = ebf + ((size_t)((bt * 2 + sub) * 32 + gf)) * 1024;
        __builtin_amdgcn_global_load_lds((const AS1 void*)(src + lane * 8),
                                         (AS3 void*)&elds[s * 1024], 16, 0, 0);
        __builtin_amdgcn_global_load_lds((const AS1 void*)(src + 512 + lane * 8),
                                         (AS3 void*)&elds[s * 1024 + 512], 16, 0, 0);
    }
    __syncthreads();

    // pair k -> local fields (lr,lc) + global n ; wave-uniform (LUT decode)
    auto pairK = [&](int k, int& lr, int& lc, int& nn) {
        int pr = wid + 8 * k;
        if (pr >= npr) pr -= npr;            // wrap: benign duplicate write
        if (type < 4) {
            const int pig = __builtin_amdgcn_readfirstlane((type & 1) * 60 + pr);
            const int byt = PAIR_T16[pig];
            lr = byt >> 4; lc = byt & 15;
        } else {
            lr = pr >> 3; lc = 8 + (pr & 7);
        }
        const int R = lr + (lr < 8 ? bLo : bHi);
        const int C = lc + (lc < 8 ? bLo : bHi);
        nn = R * (63 - R) / 2 + (C - R - 1);
    };

    auto loadW = [&](bf16x8 (&wf)[4][2], int nn) {
        const bf16x8* wp = (const bf16x8*)(kb + (size_t)nn * 4096);
#pragma unroll
        for (int mh = 0; mh < 4; ++mh)
#pragma unroll
            for (int kc = 0; kc < 2; ++kc)
                wf[mh][kc] = wp[(mh * 2 + kc) * 64 + lane];   // 1KB coalesced
    };

    auto compute = [&](bf16x8 (&wf)[4][2], int lr, int lc, int nn) {
#pragma unroll
        for (int sub = 0; sub < 2; ++sub) {
            const int bb = sub * 16 + lo4;

            // hoisted LDS reads: 2 b128 (p) + 4 b64 (q) outstanding together
            bf16x8 pf0 = *(const bf16x8*)
                &elds[(lr * 2 + sub) * 1024 + (lo4 * 8 + ((0 * 4 + hi4) ^ (lo4 & 7))) * 8];
            bf16x8 pf1 = *(const bf16x8*)
                &elds[(lr * 2 + sub) * 1024 + (lo4 * 8 + ((1 * 4 + hi4) ^ (lo4 & 7))) * 8];
            bf16x4 q0 = *(const bf16x4*)
                &elds[(lc * 2 + sub) * 1024 + (lo4 * 8 + ((0 + (hi4 >> 1)) ^ (lo4 & 7))) * 8 + (hi4 & 1) * 4];
            bf16x4 q1 = *(const bf16x4*)
                &elds[(lc * 2 + sub) * 1024 + (lo4 * 8 + ((2 + (hi4 >> 1)) ^ (lo4 & 7))) * 8 + (hi4 & 1) * 4];
            bf16x4 q2 = *(const bf16x4*)
                &elds[(lc * 2 + sub) * 1024 + (lo4 * 8 + ((4 + (hi4 >> 1)) ^ (lo4 & 7))) * 8 + (hi4 & 1) * 4];
            bf16x4 q3 = *(const bf16x4*)
                &elds[(lc * 2 + sub) * 1024 + (lo4 * 8 + ((6 + (hi4 >> 1)) ^ (lo4 & 7))) * 8 + (hi4 & 1) * 4];

            f32x4 acc[4] = {f32x4{0,0,0,0}, f32x4{0,0,0,0},
                            f32x4{0,0,0,0}, f32x4{0,0,0,0}};
            __builtin_amdgcn_s_setprio(1);
#pragma unroll
            for (int mh = 0; mh < 4; ++mh) {
                acc[mh] = __builtin_amdgcn_mfma_f32_16x16x32_bf16(
                    wf[mh][0], pf0, acc[mh], 0, 0, 0);
                acc[mh] = __builtin_amdgcn_mfma_f32_16x16x32_bf16(
                    wf[mh][1], pf1, acc[mh], 0, 0, 0);
            }
            __builtin_amdgcn_s_setprio(0);

            // epilogue: 4 independent partial dots, tree combine
            float v0 = acc[0][0] * bf2f(q0[0]);
            float v1 = acc[1][0] * bf2f(q1[0]);
            float v2 = acc[2][0] * bf2f(q2[0]);
            float v3 = acc[3][0] * bf2f(q3[0]);
            v0 = fmaf(acc[0][1], bf2f(q0[1]), v0);
            v1 = fmaf(acc[1][1], bf2f(q1[1]), v1);
            v2 = fmaf(acc[2][1], bf2f(q2[1]), v2);
            v3 = fmaf(acc[3][1], bf2f(q3[1]), v3);
            v0 = fmaf(acc[0][2], bf2f(q0[2]), v0);
            v1 = fmaf(acc[1][2], bf2f(q1[2]), v1);
            v2 = fmaf(acc[2][2], bf2f(q2[2]), v2);
            v3 = fmaf(acc[3][2], bf2f(q3[2]), v3);
            v0 = fmaf(acc[0][3], bf2f(q0[3]), v0);
            v1 = fmaf(acc[1][3], bf2f(q1[3]), v1);
            v2 = fmaf(acc[2][3], bf2f(q2[3]), v2);
            v3 = fmaf(acc[3][3], bf2f(q3[3]), v3);
            float val = (v0 + v1) + (v2 + v3);

            val += __shfl_xor(val, 16, 64);
            val += __shfl_xor(val, 32, 64);
            if (lane < 16) out[(size_t)(b0 + bb) * NP + nn] = val;
        }
    };

    // ---- 8 pairs per wave, W ping-pong double-buffered (static buffers)
    bf16x8 wA[4][2], wB[4][2];
    int lrA, lcA, nA, lrB, lcB, nB;
    pairK(0, lrA, lcA, nA);
    loadW(wA, nA);
#pragma unroll
    for (int k = 0; k < 8; ++k) {
        if ((k & 1) == 0) {
            if (k < 7) { pairK(k + 1, lrB, lcB, nB); loadW(wB, nB); }
            compute(wA, lrA, lcA, nA);
        } else {
            if (k < 7) { pairK(k + 1, lrA, lcA, nA); loadW(wA, nA); }
            compute(wB, lrB, lcB, nB);
        }
    }
}

extern "C" void kernel_launch(void* const* d_in, const int* in_sizes, int n_in,
                              void* d_out, int out_size, void* d_ws, size_t ws_size,
                              hipStream_t stream) {
    const float* emb  = (const float*)d_in[0];   // 2048*32*64
    const float* kern = (const float*)d_in[1];   // 64*496*64
    float*       out  = (float*)d_out;           // 2048*496

    short* kb  = (short*)d_ws;                          // 496*4096 bf16 ~3.9MB
    short* ebf = (short*)((char*)d_ws + (4 << 20));     // 2048*32*64 bf16 = 8MB

    prep<<<NP + (B_TOT * NF * EMB / 8) / 256, 256, 0, stream>>>(kern, emb, kb, ebf);
    opnl_main<<<8 * 64, 512, 0, stream>>>(ebf, kb, out);   // 512 blocks
}

// Round 9
// 29.310 us; speedup vs baseline: 1.0125x; 1.0125x over previous
//
#include <hip/hip_runtime.h>

// out[b,n] = q^T W_n p ; p=emb[b,R(n)], q=emb[b,C(n)], W_n=kern[:,n,:]
// R9: BT=64 + 32x32x16 MFMA.
//  - 8 types x 32 b-tiles = 256 blocks x 1024 thr (exactly 1/CU, 4 waves/SIMD).
//  - per pair: W (fragment-ordered, coalesced) reused across 64 b ->
//    W L2 traffic halved vs R8. 2 halves x 8 mfma_f32_32x32x16_bf16 (N=32=b).
//  - epilogue per half: 8 b64 q-reads + 32 FMA + ONE shfl_xor(32) + one store.
//  - 128KB static LDS, chunk-swizzled segs (2KB per (16b,field)), staged via
//    global_load_lds from pre-converted ebf.

#define B_TOT 2048
#define NF    32
#define EMB   64
#define NP    496
#define BT    64

typedef short bf16x8 __attribute__((ext_vector_type(8)));
typedef short bf16x4 __attribute__((ext_vector_type(4)));
typedef float f32x4  __attribute__((ext_vector_type(4)));
typedef float f32x16 __attribute__((ext_vector_type(16)));

static __device__ inline unsigned f2bf(float f) {          // RNE f32->bf16
    unsigned u = __builtin_bit_cast(unsigned, f);
    u += 0x7fffu + ((u >> 16) & 1u);
    return u >> 16;
}
static __device__ inline unsigned pack2(float lo, float hi) {
    return f2bf(lo) | (f2bf(hi) << 16);
}
static __device__ inline float bf2f(short s) {
    return __builtin_bit_cast(float, (unsigned)((unsigned short)s) << 16);
}

#define AS1 __attribute__((address_space(1)))
#define AS3 __attribute__((address_space(3)))

// triu16 pair decode LUT: byte = lr*16 + lc for pig 0..119
__device__ const unsigned char PAIR_T16[120] = {
    0x01,0x02,0x03,0x04,0x05,0x06,0x07,0x08,0x09,0x0A,0x0B,0x0C,0x0D,0x0E,0x0F,
    0x12,0x13,0x14,0x15,0x16,0x17,0x18,0x19,0x1A,0x1B,0x1C,0x1D,0x1E,0x1F,
    0x23,0x24,0x25,0x26,0x27,0x28,0x29,0x2A,0x2B,0x2C,0x2D,0x2E,0x2F,
    0x34,0x35,0x36,0x37,0x38,0x39,0x3A,0x3B,0x3C,0x3D,0x3E,0x3F,
    0x45,0x46,0x47,0x48,0x49,0x4A,0x4B,0x4C,0x4D,0x4E,0x4F,
    0x56,0x57,0x58,0x59,0x5A,0x5B,0x5C,0x5D,0x5E,0x5F,
    0x67,0x68,0x69,0x6A,0x6B,0x6C,0x6D,0x6E,0x6F,
    0x78,0x79,0x7A,0x7B,0x7C,0x7D,0x7E,0x7F,
    0x89,0x8A,0x8B,0x8C,0x8D,0x8E,0x8F,
    0x9A,0x9B,0x9C,0x9D,0x9E,0x9F,
    0xAB,0xAC,0xAD,0xAE,0xAF,
    0xBC,0xBD,0xBE,0xBF,
    0xCD,0xCE,0xCF,
    0xDE,0xDF,
    0xEF
};

// ---- fused prep: blocks [0,496) = kern cvt ; blocks [496, 496+2048) = emb cvt
__global__ __launch_bounds__(256) void prep(const float* __restrict__ kern,
                                            const float* __restrict__ emb,
                                            short* __restrict__ kb,
                                            short* __restrict__ ebf) {
    __shared__ short w[EMB * 72];
    if (blockIdx.x < NP) {
        // kern [h][n][e] -> 32x32x16 fragment order kb[n][frag][lane][8]
        // frag = mt*4+ks ; lane l holds W[h=mt*32+(l&31)][e=ks*16+(l>>5)*8+j]
        const int n = blockIdx.x;
#pragma unroll
        for (int j = 0; j < 4; ++j) {
            const int idx = threadIdx.x + 256 * j;        // (h, e4)
            const int h = idx >> 4, e4 = idx & 15;
            const f32x4 v = *(const f32x4*)(kern + ((size_t)h * NP + n) * EMB + e4 * 4);
            uint2 u;
            u.x = pack2(v[0], v[1]);
            u.y = pack2(v[2], v[3]);
            *(uint2*)&w[h * 72 + e4 * 4] = u;
        }
        __syncthreads();
#pragma unroll
        for (int j = 0; j < 2; ++j) {
            const int u    = threadIdx.x + 256 * j;       // fragment-lane unit
            const int frag = u >> 6, l = u & 63;
            const int h  = (frag >> 2) * 32 + (l & 31);
            const int e0 = (frag & 3) * 16 + (l >> 5) * 8;
            const bf16x8 t = *(const bf16x8*)&w[h * 72 + e0];   // 144B rows: 16B-aligned
            *(bf16x8*)(kb + (size_t)n * 4096 + u * 8) = t;
        }
    } else {
        // emb -> chunk-swizzled bf16: seg per (16b-group, field), 128 chunks,
        // chunk c = b'*8 + (e/8 ^ (b'&7))
        const int t    = (blockIdx.x - NP) * 256 + threadIdx.x;  // 0..524287
        const int cidx = t & 127;
        const int f    = (t >> 7) & 31;
        const int bt16 = t >> 12;
        const int bp = cidx >> 3, x = cidx & 7;
        const int ec = x ^ (bp & 7);
        const float* src = emb + (((size_t)(bt16 * 16 + bp) * NF + f) * EMB + ec * 8);
        const f32x4 a = *(const f32x4*)src;
        const f32x4 b = *(const f32x4*)(src + 4);
        uint4 u;
        u.x = pack2(a[0], a[1]); u.y = pack2(a[2], a[3]);
        u.z = pack2(b[0], b[1]); u.w = pack2(b[2], b[3]);
        *(uint4*)(ebf + (size_t)t * 8) = u;
    }
}

__global__ __launch_bounds__(1024) void opnl_main(
    const short* __restrict__ ebf,   // [B/16][NF][128 chunks x 8 shorts] swizzled
    const short* __restrict__ kb,    // [NP][8][64][8] bf16 32x32-fragment order
    float* __restrict__ out)         // [B][NP] f32
{
    __shared__ short elds[64 * 1024];        // 64 segs x 2KB = 128KB

    const int type = blockIdx.x >> 5;        // 0..7
    const int bt   = blockIdx.x & 31;        // 0..31
    const int b0   = bt * BT;

    int bLo, bHi, npr;
    switch (type) {
        case 0: case 1: bLo = 0;  bHi = 0;  npr = 60; break;  // fields 0..15
        case 2: case 3: bLo = 16; bHi = 16; npr = 60; break;  // fields 16..31
        case 4:         bLo = 0;  bHi = 8;  npr = 64; break;  // O0 x O2
        case 5:         bLo = 8;  bHi = 16; npr = 64; break;  // O1 x O3
        case 6:         bLo = 0;  bHi = 16; npr = 64; break;  // O0 x O3
        default:        bLo = 8;  bHi = 8;  npr = 64; break;  // O1 x O2
    }

    const int lane = threadIdx.x & 63;
    const int wid  = threadIdx.x >> 6;       // 0..15
    const int bp   = lane & 15;
    const int l5   = lane >> 5;              // 0/1
    const int sub_lo = (lane >> 4) & 1;

    // ---- stage: wave w copies segs 4w..4w+3 (seg = lf*4 + sub16), 2x 1KB each
#pragma unroll
    for (int i = 0; i < 4; ++i) {
        const int s     = wid * 4 + i;
        const int lf    = s >> 2, sub16 = s & 3;
        const int gf    = lf + (lf < 8 ? bLo : bHi);
        const short* src = ebf + ((size_t)((bt * 4 + sub16) * 32 + gf)) * 1024;
        __builtin_amdgcn_global_load_lds((const AS1 void*)(src + lane * 8),
                                         (AS3 void*)&elds[s * 1024], 16, 0, 0);
        __builtin_amdgcn_global_load_lds((const AS1 void*)(src + 512 + lane * 8),
                                         (AS3 void*)&elds[s * 1024 + 512], 16, 0, 0);
    }
    __syncthreads();

    // ---- 4 pairs per wave
    for (int k = 0; k < 4; ++k) {
        int pr = wid + 16 * k;
        if (pr >= npr) pr -= npr;            // wrap: benign duplicate write
        int lr, lc;
        if (type < 4) {
            const int pig = __builtin_amdgcn_readfirstlane((type & 1) * 60 + pr);
            const int byt = PAIR_T16[pig];
            lr = byt >> 4; lc = byt & 15;
        } else {
            lr = pr >> 3; lc = 8 + (pr & 7);
        }
        const int R  = lr + (lr < 8 ? bLo : bHi);
        const int C  = lc + (lc < 8 ? bLo : bHi);
        const int nn = R * (63 - R) / 2 + (C - R - 1);

        // W fragments: 8 coalesced 1KB loads
        bf16x8 wf[2][4];
        const bf16x8* wp = (const bf16x8*)(kb + (size_t)nn * 4096);
#pragma unroll
        for (int mt = 0; mt < 2; ++mt)
#pragma unroll
            for (int ks = 0; ks < 4; ++ks)
                wf[mt][ks] = wp[(mt * 4 + ks) * 64 + lane];

#pragma unroll
        for (int hb = 0; hb < 2; ++hb) {     // b halves of 32
            const int sub16 = hb * 2 + sub_lo;
            const int segp  = (lr * 4 + sub16) * 1024;
            const int segq  = (lc * 4 + sub16) * 1024;

            // B-frags: p[b = b0+hb*32+(lane&31)][e = ks*16 + l5*8 + j]
            bf16x8 pf[4];
#pragma unroll
            for (int ks = 0; ks < 4; ++ks) {
                const int ec = ks * 2 + l5;
                pf[ks] = *(const bf16x8*)&elds[segp + (bp * 8 + (ec ^ (bp & 7))) * 8];
            }

            f32x16 acc[2] = {
                f32x16{0,0,0,0,0,0,0,0,0,0,0,0,0,0,0,0},
                f32x16{0,0,0,0,0,0,0,0,0,0,0,0,0,0,0,0}};
#pragma unroll
            for (int ks = 0; ks < 4; ++ks) {
                acc[0] = __builtin_amdgcn_mfma_f32_32x32x16_bf16(
                    wf[0][ks], pf[ks], acc[0], 0, 0, 0);
                acc[1] = __builtin_amdgcn_mfma_f32_32x32x16_bf16(
                    wf[1][ks], pf[ks], acc[1], 0, 0, 0);
            }

            // epilogue: lane holds U[h = mt*32 + 4*l5 + 8*(reg>>2) + (reg&3), b]
            float val = 0.f;
#pragma unroll
            for (int mt = 0; mt < 2; ++mt) {
#pragma unroll
                for (int rg2 = 0; rg2 < 4; ++rg2) {
                    const bf16x4 qv = *(const bf16x4*)
                        &elds[segq + (bp * 8 + ((mt * 4 + rg2) ^ (bp & 7))) * 8 + l5 * 4];
#pragma unroll
                    for (int i = 0; i < 4; ++i)
                        val = fmaf(acc[mt][rg2 * 4 + i], bf2f(qv[i]), val);
                }
            }
            val += __shfl_xor(val, 32, 64);
            if (lane < 32) out[(size_t)(b0 + hb * 32 + lane) * NP + nn] = val;
        }
    }
}

extern "C" void kernel_launch(void* const* d_in, const int* in_sizes, int n_in,
                              void* d_out, int out_size, void* d_ws, size_t ws_size,
                              hipStream_t stream) {
    const float* emb  = (const float*)d_in[0];   // 2048*32*64
    const float* kern = (const float*)d_in[1];   // 64*496*64
    float*       out  = (float*)d_out;           // 2048*496

    short* kb  = (short*)d_ws;                          // 496*4096 bf16 ~3.9MB
    short* ebf = (short*)((char*)d_ws + (4 << 20));     // 2048*32*64 bf16 = 8MB

    prep<<<NP + (B_TOT * NF * EMB / 8) / 256, 256, 0, stream>>>(kern, emb, kb, ebf);
    opnl_main<<<8 * 32, 1024, 0, stream>>>(ebf, kb, out);   // 256 blocks, 1/CU
}